// Round 1
// baseline (583.911 us; speedup 1.0000x reference)
//
#include <hip/hip_runtime.h>
#include <hip/hip_bf16.h>
#include <stdint.h>

#define NGn 100000
#define NDn 100000
#define NEn 400000
#define ELn 200000

typedef __bf16 bf16x8 __attribute__((ext_vector_type(8)));
typedef float  f32x4  __attribute__((ext_vector_type(4)));

__device__ __forceinline__ bf16x8 cvt8(const float* __restrict__ f) {
    f32x4 a = *(const f32x4*)f;
    f32x4 b = *(const f32x4*)(f + 4);
    bf16x8 r;
    r[0] = (__bf16)a[0]; r[1] = (__bf16)a[1]; r[2] = (__bf16)a[2]; r[3] = (__bf16)a[3];
    r[4] = (__bf16)b[0]; r[5] = (__bf16)b[1]; r[6] = (__bf16)b[2]; r[7] = (__bf16)b[3];
    return r;
}

// ---------------------------------------------------------------------------
// Mask scatter: mark nodes that appear as DST of at least one edge.
// ---------------------------------------------------------------------------
__global__ void scatter_mask(const int* __restrict__ g2d_dst,
                             const int* __restrict__ d2g_dst,
                             uint8_t* __restrict__ mask_d,
                             uint8_t* __restrict__ mask_g, int n) {
    int i = blockIdx.x * blockDim.x + threadIdx.x;
    if (i < n) {
        mask_d[g2d_dst[i]] = 1;
        mask_g[d2g_dst[i]] = 1;
    }
}

// ---------------------------------------------------------------------------
// Fused node GEMM for BOTH node types in one launch.
// 512 threads (8 waves), 128-row tiles; blocks [0,half) do gene, rest disease.
// LDS 34.8 KB shared by 8 waves -> ~24-32 waves/CU (was 16 at 256 thr).
// Z[r,:] = relu(X[r,:] @ W + b) * mask[r]; f32 out + optional bf16 mirror.
// ---------------------------------------------------------------------------
__global__ __launch_bounds__(512) void node_gemm2(
    const float* __restrict__ Xg, const float* __restrict__ Wg,
    const float* __restrict__ bg, const uint8_t* __restrict__ mg,
    float* __restrict__ Zgf, __bf16* __restrict__ Zgb,
    const float* __restrict__ Xd, const float* __restrict__ Wd,
    const float* __restrict__ bd, const uint8_t* __restrict__ md,
    float* __restrict__ Zdf, __bf16* __restrict__ Zdb, int Nrows)
{
    __shared__ __bf16 Wt[128 * 136];   // Wt[c][k], stride 136 halves (16B-aligned rows)
    const int half = gridDim.x >> 1;
    const bool gene = (int)blockIdx.x < half;
    const float*   __restrict__ X    = gene ? Xg : Xd;
    const float*   __restrict__ W    = gene ? Wg : Wd;
    const float*   __restrict__ bv   = gene ? bg : bd;
    const uint8_t* __restrict__ mask = gene ? mg : md;
    float*   __restrict__ Zf = gene ? Zgf : Zdf;
    __bf16*  __restrict__ Zb = gene ? Zgb : Zdb;

    const int tid = threadIdx.x;
    for (int idx = tid; idx < 128 * 128; idx += 512) {
        int k = idx >> 7, c = idx & 127;
        Wt[c * 136 + k] = (__bf16)W[idx];
    }
    __syncthreads();

    const int wave = tid >> 6;
    const int lane = tid & 63;
    const int m = lane & 15;      // A-row within 16-row strip / D col
    const int q = lane >> 4;      // quad

    float bcol[8];
#pragma unroll
    for (int nt = 0; nt < 8; ++nt) bcol[nt] = bv[nt * 16 + m];

    const int ntiles = (Nrows + 127) >> 7;          // 782
    const int b0 = gene ? (int)blockIdx.x : (int)blockIdx.x - half;
    for (int t = b0; t < ntiles; t += half) {
        const int base = t * 128;
        const int row_a = base + wave * 16 + m;
        const int rowa_c = row_a < Nrows ? row_a : (Nrows - 1);

        f32x4 acc[8];
#pragma unroll
        for (int nt = 0; nt < 8; ++nt) acc[nt] = f32x4{0.f, 0.f, 0.f, 0.f};

#pragma unroll
        for (int kk = 0; kk < 4; ++kk) {
            bf16x8 a = cvt8(X + (size_t)rowa_c * 128 + kk * 32 + q * 8);
#pragma unroll
            for (int nt = 0; nt < 8; ++nt) {
                bf16x8 b = *(const bf16x8*)(&Wt[(nt * 16 + m) * 136 + kk * 32 + q * 8]);
                acc[nt] = __builtin_amdgcn_mfma_f32_16x16x32_bf16(a, b, acc[nt], 0, 0, 0);
            }
        }

#pragma unroll
        for (int reg = 0; reg < 4; ++reg) {
            int r = base + wave * 16 + q * 4 + reg;
            if (r < Nrows) {
                float mk = mask[r] ? 1.f : 0.f;
#pragma unroll
                for (int nt = 0; nt < 8; ++nt) {
                    float v = acc[nt][reg] + bcol[nt];
                    v = (v > 0.f ? v : 0.f) * mk;
                    Zf[(size_t)r * 128 + nt * 16 + m] = v;
                    if (Zb) Zb[(size_t)r * 128 + nt * 16 + m] = (__bf16)v;
                }
            }
        }
    }
}

// ---------------------------------------------------------------------------
// MLP over label edges. 512 threads (8 waves); LDS 64 KB -> 2 blocks/CU
// = 16 waves/CU (was 8 at 256 thr): 2x latency hiding for the random gathers.
// Work unit = 16 edges per wave; 12500 units grid-strided over all waves.
// ---------------------------------------------------------------------------
__global__ __launch_bounds__(512) void mlp2(
    const __bf16* __restrict__ zgb, const __bf16* __restrict__ zdb,
    const float* __restrict__ zgf, const float* __restrict__ zdf,
    int usebf, const int* __restrict__ eli,
    const float* __restrict__ W1, const float* __restrict__ b1,
    const float* __restrict__ W2, const float* __restrict__ b2,
    float* __restrict__ pred)
{
    __shared__ __bf16 Wt[128 * 256];   // Wt[n][k'], k' XOR-swizzled per 8-half chunk
    const int tid = threadIdx.x;
    for (int idx = tid; idx < 256 * 128; idx += 512) {
        int k = idx >> 7, c = idx & 127;
        int kc = k >> 3, kl = k & 7;
        Wt[c * 256 + ((kc ^ (c & 7)) * 8 + kl)] = (__bf16)W1[idx];
    }
    __syncthreads();

    const int wave = tid >> 6;
    const int lane = tid & 63;
    const int m = lane & 15;
    const int q = lane >> 4;

    float b1c[8], w2c[8];
#pragma unroll
    for (int nt = 0; nt < 8; ++nt) {
        b1c[nt] = b1[nt * 16 + m];
        w2c[nt] = W2[nt * 16 + m];
    }
    const float bb = b2[0];

    const int nunits = ELn >> 4;                 // 12500 units of 16 edges
    const int ustride = gridDim.x << 3;          // waves in grid
    for (int u = ((int)blockIdx.x << 3) + wave; u < nunits; u += ustride) {
        const int e = (u << 4) + m;
        const int grow = eli[e];
        const int dcol = eli[ELn + e];

        f32x4 acc[8];
#pragma unroll
        for (int nt = 0; nt < 8; ++nt) acc[nt] = f32x4{0.f, 0.f, 0.f, 0.f};

#pragma unroll
        for (int kk = 0; kk < 8; ++kk) {
            bf16x8 a;
            if (usebf) {
                const __bf16* src = (kk < 4) ? (zgb + (size_t)grow * 128 + kk * 32)
                                             : (zdb + (size_t)dcol * 128 + (kk - 4) * 32);
                a = *(const bf16x8*)(src + q * 8);
            } else {
                const float* src = (kk < 4) ? (zgf + (size_t)grow * 128 + kk * 32)
                                            : (zdf + (size_t)dcol * 128 + (kk - 4) * 32);
                a = cvt8(src + q * 8);
            }
            const int kcr = kk * 4 + q;
#pragma unroll
            for (int nt = 0; nt < 8; ++nt) {
                int n = nt * 16 + m;
                bf16x8 b = *(const bf16x8*)(&Wt[n * 256 + ((kcr ^ (n & 7)) * 8)]);
                acc[nt] = __builtin_amdgcn_mfma_f32_16x16x32_bf16(a, b, acc[nt], 0, 0, 0);
            }
        }

        float pb[4];
#pragma unroll
        for (int reg = 0; reg < 4; ++reg) {
            float s = 0.f;
#pragma unroll
            for (int nt = 0; nt < 8; ++nt) {
                float h = acc[nt][reg] + b1c[nt];
                h = h > 0.f ? h : 0.f;
                s += h * w2c[nt];
            }
            pb[reg] = s;
        }
#pragma unroll
        for (int off = 1; off < 16; off <<= 1) {
#pragma unroll
            for (int reg = 0; reg < 4; ++reg)
                pb[reg] += __shfl_xor(pb[reg], off, 64);
        }
        if (m == 0) {
#pragma unroll
            for (int reg = 0; reg < 4; ++reg)
                pred[(u << 4) + q * 4 + reg] = pb[reg] + bb;
        }
    }
}

// ---------------------------------------------------------------------------
extern "C" void kernel_launch(void* const* d_in, const int* in_sizes, int n_in,
                              void* d_out, int out_size, void* d_ws, size_t ws_size,
                              hipStream_t stream) {
    const float* x_gene    = (const float*)d_in[0];
    const float* x_disease = (const float*)d_in[1];
    const int*   ei_g2d    = (const int*)d_in[2];
    const int*   ei_d2g    = (const int*)d_in[3];
    const int*   eli       = (const int*)d_in[6];
    const float* Wn_gene   = (const float*)d_in[7];
    const float* bn_gene   = (const float*)d_in[8];
    const float* Wn_dis    = (const float*)d_in[9];
    const float* bn_dis    = (const float*)d_in[10];
    const float* W1        = (const float*)d_in[17];
    const float* b1        = (const float*)d_in[18];
    const float* W2        = (const float*)d_in[19];
    const float* b2        = (const float*)d_in[20];

    float* out   = (float*)d_out;
    float* predp = out;                                   // [200000]
    float* zgf   = out + ELn;                             // [100000*128]
    float* zdf   = zgf + (size_t)NGn * 128;               // [100000*128]

    uint8_t* mask_d = (uint8_t*)d_ws;                     // [ND]
    uint8_t* mask_g = mask_d + NDn;                       // [NG]

    const size_t zelems = (size_t)NGn * 128;              // 12.8M
    const size_t mirror_off = 200704;                     // masks, 256-aligned
    const bool   mirror = ws_size >= mirror_off + 2 * zelems * sizeof(__bf16);
    __bf16* zgb = mirror ? (__bf16*)((char*)d_ws + mirror_off) : nullptr;
    __bf16* zdb = mirror ? zgb + zelems : nullptr;

    hipMemsetAsync(d_ws, 0, NGn + NDn, stream);
    scatter_mask<<<(NEn + 255) / 256, 256, 0, stream>>>(
        ei_g2d + NEn, ei_d2g + NEn, mask_d, mask_g, NEn);

    // 782 tiles per side, one per block: grid = 2*782
    node_gemm2<<<1564, 512, 0, stream>>>(
        x_gene, Wn_gene, bn_gene, mask_g, zgf, zgb,
        x_disease, Wn_dis, bn_dis, mask_d, zdf, zdb, NGn);

    mlp2<<<512, 512, 0, stream>>>(zgb, zdb, zgf, zdf, mirror ? 1 : 0,
                                  eli, W1, b1, W2, b2, predp);
}

// Round 2
// 525.009 us; speedup vs baseline: 1.1122x; 1.1122x over previous
//
#include <hip/hip_runtime.h>
#include <hip/hip_bf16.h>
#include <stdint.h>

#define NGn 100000
#define NDn 100000
#define NEn 400000
#define ELn 200000

typedef __bf16 bf16x8 __attribute__((ext_vector_type(8)));
typedef float  f32x4  __attribute__((ext_vector_type(4)));

__device__ __forceinline__ bf16x8 cvt8(const float* __restrict__ f) {
    f32x4 a = *(const f32x4*)f;
    f32x4 b = *(const f32x4*)(f + 4);
    bf16x8 r;
    r[0] = (__bf16)a[0]; r[1] = (__bf16)a[1]; r[2] = (__bf16)a[2]; r[3] = (__bf16)a[3];
    r[4] = (__bf16)b[0]; r[5] = (__bf16)b[1]; r[6] = (__bf16)b[2]; r[7] = (__bf16)b[3];
    return r;
}

// ---------------------------------------------------------------------------
// Mask scatter: mark nodes that appear as DST of at least one edge.
// ---------------------------------------------------------------------------
__global__ void scatter_mask(const int* __restrict__ g2d_dst,
                             const int* __restrict__ d2g_dst,
                             uint8_t* __restrict__ mask_d,
                             uint8_t* __restrict__ mask_g, int n) {
    int i = blockIdx.x * blockDim.x + threadIdx.x;
    if (i < n) {
        mask_d[g2d_dst[i]] = 1;
        mask_g[d2g_dst[i]] = 1;
    }
}

// ---------------------------------------------------------------------------
// Z[r,:] = relu(X[r,:] @ W + b) * mask[r].  (round-0 proven version)
// ---------------------------------------------------------------------------
__global__ __launch_bounds__(256) void node_gemm(
    const float* __restrict__ X, const float* __restrict__ W,
    const float* __restrict__ bias, const uint8_t* __restrict__ mask,
    float* __restrict__ Zf, __bf16* __restrict__ Zb, int Nrows)
{
    __shared__ __bf16 Wt[128 * 136];   // Wt[c][k], stride 136 halves
    const int tid = threadIdx.x;
    for (int idx = tid; idx < 128 * 128; idx += 256) {
        int k = idx >> 7, c = idx & 127;
        Wt[c * 136 + k] = (__bf16)W[idx];
    }
    __syncthreads();

    const int wave = tid >> 6;
    const int lane = tid & 63;
    const int m = lane & 15;      // A-row within tile / D col
    const int q = lane >> 4;      // quad

    float bcol[8];
#pragma unroll
    for (int nt = 0; nt < 8; ++nt) bcol[nt] = bias[nt * 16 + m];

    const int ntiles = (Nrows + 63) >> 6;
    for (int t = blockIdx.x; t < ntiles; t += gridDim.x) {
        const int base = t * 64;
        const int row_a = base + wave * 16 + m;
        const int rowa_c = row_a < Nrows ? row_a : (Nrows - 1);

        f32x4 acc[8];
#pragma unroll
        for (int nt = 0; nt < 8; ++nt) acc[nt] = f32x4{0.f, 0.f, 0.f, 0.f};

#pragma unroll
        for (int kk = 0; kk < 4; ++kk) {
            bf16x8 a = cvt8(X + (size_t)rowa_c * 128 + kk * 32 + q * 8);
#pragma unroll
            for (int nt = 0; nt < 8; ++nt) {
                bf16x8 b = *(const bf16x8*)(&Wt[(nt * 16 + m) * 136 + kk * 32 + q * 8]);
                acc[nt] = __builtin_amdgcn_mfma_f32_16x16x32_bf16(a, b, acc[nt], 0, 0, 0);
            }
        }

#pragma unroll
        for (int reg = 0; reg < 4; ++reg) {
            int r = base + wave * 16 + q * 4 + reg;
            if (r < Nrows) {
                float mk = mask[r] ? 1.f : 0.f;
#pragma unroll
                for (int nt = 0; nt < 8; ++nt) {
                    float v = acc[nt][reg] + bcol[nt];
                    v = (v > 0.f ? v : 0.f) * mk;
                    Zf[(size_t)r * 128 + nt * 16 + m] = v;
                    if (Zb) Zb[(size_t)r * 128 + nt * 16 + m] = (__bf16)v;
                }
            }
        }
    }
}

// ---------------------------------------------------------------------------
// Dense H-GEMM: Hg = Zg @ W1[:128], Hd = Zd @ W1[128:].  Both halves in one
// launch (blocks [0,half) = gene).  A is bf16 mirror (no cvt), output bf16
// mirror only.  No bias (b1 added in edge pass), no relu.
// ---------------------------------------------------------------------------
__global__ __launch_bounds__(256) void h_gemm(
    const __bf16* __restrict__ Zgb, const __bf16* __restrict__ Zdb,
    const float* __restrict__ W1,
    __bf16* __restrict__ Hgb, __bf16* __restrict__ Hdb)
{
    __shared__ __bf16 Wt[128 * 136];   // Wt[c][k]
    const int half = gridDim.x >> 1;
    const bool gene = (int)blockIdx.x < half;
    const __bf16* __restrict__ Z = gene ? Zgb : Zdb;
    __bf16*       __restrict__ H = gene ? Hgb : Hdb;
    const float*  __restrict__ Ws = W1 + (gene ? 0 : 128 * 128);

    const int tid = threadIdx.x;
    for (int idx = tid; idx < 128 * 128; idx += 256) {
        int k = idx >> 7, c = idx & 127;
        Wt[c * 136 + k] = (__bf16)Ws[idx];
    }
    __syncthreads();

    const int wave = tid >> 6;
    const int lane = tid & 63;
    const int m = lane & 15;
    const int q = lane >> 4;

    const int ntiles = (NGn + 63) >> 6;            // 1563 (both sides 100k)
    const int b0 = gene ? (int)blockIdx.x : (int)blockIdx.x - half;
    for (int t = b0; t < ntiles; t += half) {
        const int base = t * 64;
        const int row_a = base + wave * 16 + m;
        const int rowa_c = row_a < NGn ? row_a : (NGn - 1);

        f32x4 acc[8];
#pragma unroll
        for (int nt = 0; nt < 8; ++nt) acc[nt] = f32x4{0.f, 0.f, 0.f, 0.f};

#pragma unroll
        for (int kk = 0; kk < 4; ++kk) {
            bf16x8 a = *(const bf16x8*)(Z + (size_t)rowa_c * 128 + kk * 32 + q * 8);
#pragma unroll
            for (int nt = 0; nt < 8; ++nt) {
                bf16x8 b = *(const bf16x8*)(&Wt[(nt * 16 + m) * 136 + kk * 32 + q * 8]);
                acc[nt] = __builtin_amdgcn_mfma_f32_16x16x32_bf16(a, b, acc[nt], 0, 0, 0);
            }
        }

#pragma unroll
        for (int reg = 0; reg < 4; ++reg) {
            int r = base + wave * 16 + q * 4 + reg;
            if (r < NGn) {
#pragma unroll
                for (int nt = 0; nt < 8; ++nt)
                    H[(size_t)r * 128 + nt * 16 + m] = (__bf16)acc[nt][reg];
            }
        }
    }
}

// ---------------------------------------------------------------------------
// Edge pass: pred[e] = relu(Hg[row]+Hd[col]+b1) . W2 + b2.
// Pure gather + VALU: no LDS, no MFMA -> max occupancy, latency-tolerant.
// 16 lanes per edge (8 channels/lane); 8 edges per wave-iteration.
// ---------------------------------------------------------------------------
__global__ __launch_bounds__(256) void edge_mlp(
    const __bf16* __restrict__ Hgb, const __bf16* __restrict__ Hdb,
    const int* __restrict__ eli, const float* __restrict__ b1,
    const float* __restrict__ W2, const float* __restrict__ b2,
    float* __restrict__ pred)
{
    const int tid = threadIdx.x;
    const int wave = tid >> 6;
    const int lane = tid & 63;
    const int l16 = lane & 15;        // channel group: 8 ch per lane
    const int sub = lane >> 4;        // edge sub-slot 0..3

    float b1c[8], w2c[8];
#pragma unroll
    for (int j = 0; j < 8; ++j) {
        b1c[j] = b1[l16 * 8 + j];
        w2c[j] = W2[l16 * 8 + j];
    }
    const float bb = b2[0];

    const int nunits = ELn >> 3;                   // 25000 units of 8 edges
    const int wid0 = (int)blockIdx.x * 4 + wave;
    const int wstride = (int)gridDim.x * 4;
    for (int u = wid0; u < nunits; u += wstride) {
        const int e0 = u * 8 + sub * 2;
        const int g0 = eli[e0],       g1 = eli[e0 + 1];
        const int d0 = eli[ELn + e0], d1 = eli[ELn + e0 + 1];

        bf16x8 vg0 = *(const bf16x8*)(Hgb + (size_t)g0 * 128 + l16 * 8);
        bf16x8 vd0 = *(const bf16x8*)(Hdb + (size_t)d0 * 128 + l16 * 8);
        bf16x8 vg1 = *(const bf16x8*)(Hgb + (size_t)g1 * 128 + l16 * 8);
        bf16x8 vd1 = *(const bf16x8*)(Hdb + (size_t)d1 * 128 + l16 * 8);

        float s0 = 0.f, s1 = 0.f;
#pragma unroll
        for (int j = 0; j < 8; ++j) {
            float h0 = (float)vg0[j] + (float)vd0[j] + b1c[j];
            float h1 = (float)vg1[j] + (float)vd1[j] + b1c[j];
            h0 = h0 > 0.f ? h0 : 0.f;
            h1 = h1 > 0.f ? h1 : 0.f;
            s0 += h0 * w2c[j];
            s1 += h1 * w2c[j];
        }
#pragma unroll
        for (int off = 1; off < 16; off <<= 1) {
            s0 += __shfl_xor(s0, off, 64);
            s1 += __shfl_xor(s1, off, 64);
        }
        if (l16 == 0) {
            pred[e0]     = s0 + bb;
            pred[e0 + 1] = s1 + bb;
        }
    }
}

// ---------------------------------------------------------------------------
// Fallback edge MLP (round-0 proven): gathered z @ W1 via MFMA.  Used only
// if the workspace cannot hold the 4 bf16 mirrors.
// ---------------------------------------------------------------------------
__global__ __launch_bounds__(256) void mlp_kernel(
    const __bf16* __restrict__ zgb, const __bf16* __restrict__ zdb,
    const float* __restrict__ zgf, const float* __restrict__ zdf,
    int usebf, const int* __restrict__ eli,
    const float* __restrict__ W1, const float* __restrict__ b1,
    const float* __restrict__ W2, const float* __restrict__ b2,
    float* __restrict__ pred)
{
    __shared__ __bf16 Wt[128 * 256];
    const int tid = threadIdx.x;
    for (int idx = tid; idx < 256 * 128; idx += 256) {
        int k = idx >> 7, c = idx & 127;
        int kc = k >> 3, kl = k & 7;
        Wt[c * 256 + ((kc ^ (c & 7)) * 8 + kl)] = (__bf16)W1[idx];
    }
    __syncthreads();

    const int wave = tid >> 6;
    const int lane = tid & 63;
    const int m = lane & 15;
    const int q = lane >> 4;

    float b1c[8], w2c[8];
#pragma unroll
    for (int nt = 0; nt < 8; ++nt) {
        b1c[nt] = b1[nt * 16 + m];
        w2c[nt] = W2[nt * 16 + m];
    }
    const float bb = b2[0];

    const int ngroups = ELn / 64;
    for (int g = blockIdx.x; g < ngroups; g += gridDim.x) {
        const int e = g * 64 + wave * 16 + m;
        const int grow = eli[e];
        const int dcol = eli[ELn + e];

        f32x4 acc[8];
#pragma unroll
        for (int nt = 0; nt < 8; ++nt) acc[nt] = f32x4{0.f, 0.f, 0.f, 0.f};

#pragma unroll
        for (int kk = 0; kk < 8; ++kk) {
            bf16x8 a;
            if (usebf) {
                const __bf16* src = (kk < 4) ? (zgb + (size_t)grow * 128 + kk * 32)
                                             : (zdb + (size_t)dcol * 128 + (kk - 4) * 32);
                a = *(const bf16x8*)(src + q * 8);
            } else {
                const float* src = (kk < 4) ? (zgf + (size_t)grow * 128 + kk * 32)
                                            : (zdf + (size_t)dcol * 128 + (kk - 4) * 32);
                a = cvt8(src + q * 8);
            }
            const int kcr = kk * 4 + q;
#pragma unroll
            for (int nt = 0; nt < 8; ++nt) {
                int n = nt * 16 + m;
                bf16x8 b = *(const bf16x8*)(&Wt[n * 256 + ((kcr ^ (n & 7)) * 8)]);
                acc[nt] = __builtin_amdgcn_mfma_f32_16x16x32_bf16(a, b, acc[nt], 0, 0, 0);
            }
        }

        float pb[4];
#pragma unroll
        for (int reg = 0; reg < 4; ++reg) {
            float s = 0.f;
#pragma unroll
            for (int nt = 0; nt < 8; ++nt) {
                float h = acc[nt][reg] + b1c[nt];
                h = h > 0.f ? h : 0.f;
                s += h * w2c[nt];
            }
            pb[reg] = s;
        }
#pragma unroll
        for (int off = 1; off < 16; off <<= 1) {
#pragma unroll
            for (int reg = 0; reg < 4; ++reg)
                pb[reg] += __shfl_xor(pb[reg], off, 64);
        }
        if (m == 0) {
#pragma unroll
            for (int reg = 0; reg < 4; ++reg) {
                int er = g * 64 + wave * 16 + q * 4 + reg;
                pred[er] = pb[reg] + bb;
            }
        }
    }
}

// ---------------------------------------------------------------------------
extern "C" void kernel_launch(void* const* d_in, const int* in_sizes, int n_in,
                              void* d_out, int out_size, void* d_ws, size_t ws_size,
                              hipStream_t stream) {
    const float* x_gene    = (const float*)d_in[0];
    const float* x_disease = (const float*)d_in[1];
    const int*   ei_g2d    = (const int*)d_in[2];
    const int*   ei_d2g    = (const int*)d_in[3];
    const int*   eli       = (const int*)d_in[6];
    const float* Wn_gene   = (const float*)d_in[7];
    const float* bn_gene   = (const float*)d_in[8];
    const float* Wn_dis    = (const float*)d_in[9];
    const float* bn_dis    = (const float*)d_in[10];
    const float* W1        = (const float*)d_in[17];
    const float* b1        = (const float*)d_in[18];
    const float* W2        = (const float*)d_in[19];
    const float* b2        = (const float*)d_in[20];

    float* out   = (float*)d_out;
    float* predp = out;                                   // [200000]
    float* zgf   = out + ELn;                             // [100000*128]
    float* zdf   = zgf + (size_t)NGn * 128;               // [100000*128]

    uint8_t* mask_d = (uint8_t*)d_ws;                     // [ND]
    uint8_t* mask_g = mask_d + NDn;                       // [NG]

    const size_t zelems = (size_t)NGn * 128;              // 12.8M
    const size_t mirror_off = 200704;                     // masks, 256-aligned
    const bool   mirror2 = ws_size >= mirror_off + 2 * zelems * sizeof(__bf16);
    const bool   mirror4 = ws_size >= mirror_off + 4 * zelems * sizeof(__bf16);
    __bf16* zgb = mirror2 ? (__bf16*)((char*)d_ws + mirror_off) : nullptr;
    __bf16* zdb = mirror2 ? zgb + zelems : nullptr;
    __bf16* Hgb = mirror4 ? zdb + zelems : nullptr;
    __bf16* Hdb = mirror4 ? Hgb + zelems : nullptr;

    hipMemsetAsync(d_ws, 0, NGn + NDn, stream);
    scatter_mask<<<(NEn + 255) / 256, 256, 0, stream>>>(
        ei_g2d + NEn, ei_d2g + NEn, mask_d, mask_g, NEn);

    node_gemm<<<1024, 256, 0, stream>>>(x_gene, Wn_gene, bn_gene, mask_g, zgf, zgb, NGn);
    node_gemm<<<1024, 256, 0, stream>>>(x_disease, Wn_dis, bn_dis, mask_d, zdf, zdb, NDn);

    if (mirror4) {
        h_gemm<<<2048, 256, 0, stream>>>(zgb, zdb, W1, Hgb, Hdb);
        edge_mlp<<<2048, 256, 0, stream>>>(Hgb, Hdb, eli, b1, W2, b2, predp);
    } else {
        mlp_kernel<<<512, 256, 0, stream>>>(zgb, zdb, zgf, zdf, mirror2 ? 1 : 0,
                                            eli, W1, b1, W2, b2, predp);
    }
}

// Round 4
// 499.267 us; speedup vs baseline: 1.1695x; 1.0516x over previous
//
#include <hip/hip_runtime.h>
#include <hip/hip_bf16.h>
#include <stdint.h>

#define NGn 100000
#define NDn 100000
#define NEn 400000
#define ELn 200000

typedef __bf16 bf16x8 __attribute__((ext_vector_type(8)));
typedef float  f32x4  __attribute__((ext_vector_type(4)));

__device__ __forceinline__ bf16x8 cvt8(const float* __restrict__ f) {
    f32x4 a = *(const f32x4*)f;
    f32x4 b = *(const f32x4*)(f + 4);
    bf16x8 r;
    r[0] = (__bf16)a[0]; r[1] = (__bf16)a[1]; r[2] = (__bf16)a[2]; r[3] = (__bf16)a[3];
    r[4] = (__bf16)b[0]; r[5] = (__bf16)b[1]; r[6] = (__bf16)b[2]; r[7] = (__bf16)b[3];
    return r;
}

// XOR-chunk swizzle for a [row][128-half] bf16 LDS tile: keeps 8-half chunks
// contiguous (b128-readable) while spreading same-column reads across banks.
__device__ __forceinline__ int swz(int row, int col) {
    return row * 128 + ((((col >> 3) ^ (row & 7)) << 3) | (col & 7));
}

// ---------------------------------------------------------------------------
// Mask scatter: mark nodes that appear as DST of at least one edge.
// ---------------------------------------------------------------------------
__global__ void scatter_mask(const int* __restrict__ g2d_dst,
                             const int* __restrict__ d2g_dst,
                             uint8_t* __restrict__ mask_d,
                             uint8_t* __restrict__ mask_g, int n) {
    int i = blockIdx.x * blockDim.x + threadIdx.x;
    if (i < n) {
        mask_d[g2d_dst[i]] = 1;
        mask_g[d2g_dst[i]] = 1;
    }
}

// ---------------------------------------------------------------------------
// Fused node+H kernel (resubmission of round-3 source; round-3 bench was an
// infra container failure, not a kernel failure).  Per 64-row tile:
//   stage 1: Z = relu(X @ Wn + b) * mask   -> Zf (f32 out), bf16 tile in LDS
//   stage 2: H = Zbf16 @ W1half            -> H (bf16 ws mirror)
// The D-layout -> A-fragment transpose goes through a per-wave 16x128 LDS
// slot (XOR-swizzled).  LDS = 32K WnT + 32K W1T + 16K ztile = 80 KB
// -> 2 blocks/CU (8 waves/CU).  Blocks [0,half) = gene side.
// ---------------------------------------------------------------------------
__global__ __launch_bounds__(256) void fused_node_h(
    const float* __restrict__ Xg, const float* __restrict__ Wng,
    const float* __restrict__ bng, const uint8_t* __restrict__ mg,
    float* __restrict__ Zgf, __bf16* __restrict__ Hgb,
    const float* __restrict__ Xd, const float* __restrict__ Wnd,
    const float* __restrict__ bnd, const uint8_t* __restrict__ md,
    float* __restrict__ Zdf, __bf16* __restrict__ Hdb,
    const float* __restrict__ W1)
{
    __shared__ __bf16 WnT[128 * 128];     // swizzled [n][k]
    __shared__ __bf16 W1T[128 * 128];     // swizzled [n][k]
    __shared__ __bf16 zt[4][16 * 128];    // per-wave swizzled [row][k]

    const int half = gridDim.x >> 1;
    const bool gene = (int)blockIdx.x < half;
    const float*   __restrict__ X    = gene ? Xg : Xd;
    const float*   __restrict__ Wn   = gene ? Wng : Wnd;
    const float*   __restrict__ bv   = gene ? bng : bnd;
    const uint8_t* __restrict__ mask = gene ? mg : md;
    float*  __restrict__ Zf = gene ? Zgf : Zdf;
    __bf16* __restrict__ H  = gene ? Hgb : Hdb;
    const float* __restrict__ W1s = W1 + (gene ? 0 : 128 * 128);

    const int tid = threadIdx.x;
    for (int idx = tid; idx < 128 * 128; idx += 256) {
        int k = idx >> 7, c = idx & 127;        // coalesced global reads
        WnT[swz(c, k)] = (__bf16)Wn[idx];
        W1T[swz(c, k)] = (__bf16)W1s[idx];
    }
    __syncthreads();

    const int wave = tid >> 6;
    const int lane = tid & 63;
    const int m = lane & 15;      // A-row within 16-row strip / D col
    const int q = lane >> 4;      // quad
    __bf16* zw = zt[wave];

    float bcol[8];
#pragma unroll
    for (int nt = 0; nt < 8; ++nt) bcol[nt] = bv[nt * 16 + m];

    const int ntiles = (NGn + 63) >> 6;        // 1563 (both sides 100k rows)
    const int b0 = gene ? (int)blockIdx.x : (int)blockIdx.x - half;
    for (int t = b0; t < ntiles; t += half) {
        const int base = t * 64;
        const int row_a = base + wave * 16 + m;
        const int rowa_c = row_a < NGn ? row_a : (NGn - 1);

        // ---- stage 1: Z-tile ----
        f32x4 acc[8];
#pragma unroll
        for (int nt = 0; nt < 8; ++nt) acc[nt] = f32x4{0.f, 0.f, 0.f, 0.f};

#pragma unroll
        for (int kk = 0; kk < 4; ++kk) {
            bf16x8 a = cvt8(X + (size_t)rowa_c * 128 + kk * 32 + q * 8);
#pragma unroll
            for (int nt = 0; nt < 8; ++nt) {
                bf16x8 b = *(const bf16x8*)(&WnT[swz(nt * 16 + m, kk * 32 + q * 8)]);
                acc[nt] = __builtin_amdgcn_mfma_f32_16x16x32_bf16(a, b, acc[nt], 0, 0, 0);
            }
        }

        // epilogue 1: bias+relu+mask; Zf out; bf16 into per-wave LDS slot
#pragma unroll
        for (int reg = 0; reg < 4; ++reg) {
            const int rr = q * 4 + reg;            // row within wave strip
            const int r  = base + wave * 16 + rr;  // global row
            const bool ok = r < NGn;
            const float mk = (ok && mask[ok ? r : 0]) ? 1.f : 0.f;
#pragma unroll
            for (int nt = 0; nt < 8; ++nt) {
                float v = acc[nt][reg] + bcol[nt];
                v = (v > 0.f ? v : 0.f) * mk;
                if (ok) Zf[(size_t)r * 128 + nt * 16 + m] = v;
                zw[swz(rr, nt * 16 + m)] = (__bf16)v;
            }
        }
        __syncthreads();   // LDS writes visible (also fences prev-iter reads)

        // ---- stage 2: H-tile = Ztile @ W1half ----
        f32x4 acc2[8];
#pragma unroll
        for (int nt = 0; nt < 8; ++nt) acc2[nt] = f32x4{0.f, 0.f, 0.f, 0.f};

#pragma unroll
        for (int kk = 0; kk < 4; ++kk) {
            bf16x8 a2 = *(const bf16x8*)(&zw[swz(m, kk * 32 + q * 8)]);
#pragma unroll
            for (int nt = 0; nt < 8; ++nt) {
                bf16x8 b2 = *(const bf16x8*)(&W1T[swz(nt * 16 + m, kk * 32 + q * 8)]);
                acc2[nt] = __builtin_amdgcn_mfma_f32_16x16x32_bf16(a2, b2, acc2[nt], 0, 0, 0);
            }
        }

#pragma unroll
        for (int reg = 0; reg < 4; ++reg) {
            const int r = base + wave * 16 + q * 4 + reg;
            if (r < NGn) {
#pragma unroll
                for (int nt = 0; nt < 8; ++nt)
                    H[(size_t)r * 128 + nt * 16 + m] = (__bf16)acc2[nt][reg];
            }
        }
        __syncthreads();   // protect zt before next tile's writes
    }
}

// ---------------------------------------------------------------------------
// Edge pass: pred[e] = relu(Hg[row]+Hd[col]+b1) . W2 + b2.
// Pure gather + VALU: no LDS, no MFMA -> max occupancy, latency-tolerant.
// ---------------------------------------------------------------------------
__global__ __launch_bounds__(256) void edge_mlp(
    const __bf16* __restrict__ Hgb, const __bf16* __restrict__ Hdb,
    const int* __restrict__ eli, const float* __restrict__ b1,
    const float* __restrict__ W2, const float* __restrict__ b2,
    float* __restrict__ pred)
{
    const int tid = threadIdx.x;
    const int wave = tid >> 6;
    const int lane = tid & 63;
    const int l16 = lane & 15;        // channel group: 8 ch per lane
    const int sub = lane >> 4;        // edge sub-slot 0..3

    float b1c[8], w2c[8];
#pragma unroll
    for (int j = 0; j < 8; ++j) {
        b1c[j] = b1[l16 * 8 + j];
        w2c[j] = W2[l16 * 8 + j];
    }
    const float bb = b2[0];

    const int nunits = ELn >> 3;                   // 25000 units of 8 edges
    const int wid0 = (int)blockIdx.x * 4 + wave;
    const int wstride = (int)gridDim.x * 4;
    for (int u = wid0; u < nunits; u += wstride) {
        const int e0 = u * 8 + sub * 2;
        const int g0 = eli[e0],       g1 = eli[e0 + 1];
        const int d0 = eli[ELn + e0], d1 = eli[ELn + e0 + 1];

        bf16x8 vg0 = *(const bf16x8*)(Hgb + (size_t)g0 * 128 + l16 * 8);
        bf16x8 vd0 = *(const bf16x8*)(Hdb + (size_t)d0 * 128 + l16 * 8);
        bf16x8 vg1 = *(const bf16x8*)(Hgb + (size_t)g1 * 128 + l16 * 8);
        bf16x8 vd1 = *(const bf16x8*)(Hdb + (size_t)d1 * 128 + l16 * 8);

        float s0 = 0.f, s1 = 0.f;
#pragma unroll
        for (int j = 0; j < 8; ++j) {
            float h0 = (float)vg0[j] + (float)vd0[j] + b1c[j];
            float h1 = (float)vg1[j] + (float)vd1[j] + b1c[j];
            h0 = h0 > 0.f ? h0 : 0.f;
            h1 = h1 > 0.f ? h1 : 0.f;
            s0 += h0 * w2c[j];
            s1 += h1 * w2c[j];
        }
#pragma unroll
        for (int off = 1; off < 16; off <<= 1) {
            s0 += __shfl_xor(s0, off, 64);
            s1 += __shfl_xor(s1, off, 64);
        }
        if (l16 == 0) {
            pred[e0]     = s0 + bb;
            pred[e0 + 1] = s1 + bb;
        }
    }
}

// ---------------------------------------------------------------------------
// Fallback path (only if workspace can't hold the H mirrors): round-0 node
// GEMM (f32 out only) + MFMA edge MLP reading f32 Z.
// ---------------------------------------------------------------------------
__global__ __launch_bounds__(256) void node_gemm(
    const float* __restrict__ X, const float* __restrict__ W,
    const float* __restrict__ bias, const uint8_t* __restrict__ mask,
    float* __restrict__ Zf, int Nrows)
{
    __shared__ __bf16 Wt[128 * 136];
    const int tid = threadIdx.x;
    for (int idx = tid; idx < 128 * 128; idx += 256) {
        int k = idx >> 7, c = idx & 127;
        Wt[c * 136 + k] = (__bf16)W[idx];
    }
    __syncthreads();

    const int wave = tid >> 6;
    const int lane = tid & 63;
    const int m = lane & 15;
    const int q = lane >> 4;

    float bcol[8];
#pragma unroll
    for (int nt = 0; nt < 8; ++nt) bcol[nt] = bias[nt * 16 + m];

    const int ntiles = (Nrows + 63) >> 6;
    for (int t = blockIdx.x; t < ntiles; t += gridDim.x) {
        const int base = t * 64;
        const int row_a = base + wave * 16 + m;
        const int rowa_c = row_a < Nrows ? row_a : (Nrows - 1);

        f32x4 acc[8];
#pragma unroll
        for (int nt = 0; nt < 8; ++nt) acc[nt] = f32x4{0.f, 0.f, 0.f, 0.f};

#pragma unroll
        for (int kk = 0; kk < 4; ++kk) {
            bf16x8 a = cvt8(X + (size_t)rowa_c * 128 + kk * 32 + q * 8);
#pragma unroll
            for (int nt = 0; nt < 8; ++nt) {
                bf16x8 b = *(const bf16x8*)(&Wt[(nt * 16 + m) * 136 + kk * 32 + q * 8]);
                acc[nt] = __builtin_amdgcn_mfma_f32_16x16x32_bf16(a, b, acc[nt], 0, 0, 0);
            }
        }

#pragma unroll
        for (int reg = 0; reg < 4; ++reg) {
            int r = base + wave * 16 + q * 4 + reg;
            if (r < Nrows) {
                float mk = mask[r] ? 1.f : 0.f;
#pragma unroll
                for (int nt = 0; nt < 8; ++nt) {
                    float v = acc[nt][reg] + bcol[nt];
                    v = (v > 0.f ? v : 0.f) * mk;
                    Zf[(size_t)r * 128 + nt * 16 + m] = v;
                }
            }
        }
    }
}

__global__ __launch_bounds__(256) void mlp_kernel(
    const float* __restrict__ zgf, const float* __restrict__ zdf,
    const int* __restrict__ eli,
    const float* __restrict__ W1, const float* __restrict__ b1,
    const float* __restrict__ W2, const float* __restrict__ b2,
    float* __restrict__ pred)
{
    __shared__ __bf16 Wt[128 * 256];
    const int tid = threadIdx.x;
    for (int idx = tid; idx < 256 * 128; idx += 256) {
        int k = idx >> 7, c = idx & 127;
        int kc = k >> 3, kl = k & 7;
        Wt[c * 256 + ((kc ^ (c & 7)) * 8 + kl)] = (__bf16)W1[idx];
    }
    __syncthreads();

    const int wave = tid >> 6;
    const int lane = tid & 63;
    const int m = lane & 15;
    const int q = lane >> 4;

    float b1c[8], w2c[8];
#pragma unroll
    for (int nt = 0; nt < 8; ++nt) {
        b1c[nt] = b1[nt * 16 + m];
        w2c[nt] = W2[nt * 16 + m];
    }
    const float bb = b2[0];

    const int ngroups = ELn / 64;
    for (int g = blockIdx.x; g < ngroups; g += gridDim.x) {
        const int e = g * 64 + wave * 16 + m;
        const int grow = eli[e];
        const int dcol = eli[ELn + e];

        f32x4 acc[8];
#pragma unroll
        for (int nt = 0; nt < 8; ++nt) acc[nt] = f32x4{0.f, 0.f, 0.f, 0.f};

#pragma unroll
        for (int kk = 0; kk < 8; ++kk) {
            const float* src = (kk < 4) ? (zgf + (size_t)grow * 128 + kk * 32)
                                        : (zdf + (size_t)dcol * 128 + (kk - 4) * 32);
            bf16x8 a = cvt8(src + q * 8);
            const int kcr = kk * 4 + q;
#pragma unroll
            for (int nt = 0; nt < 8; ++nt) {
                int n = nt * 16 + m;
                bf16x8 b = *(const bf16x8*)(&Wt[n * 256 + ((kcr ^ (n & 7)) * 8)]);
                acc[nt] = __builtin_amdgcn_mfma_f32_16x16x32_bf16(a, b, acc[nt], 0, 0, 0);
            }
        }

        float pb[4];
#pragma unroll
        for (int reg = 0; reg < 4; ++reg) {
            float s = 0.f;
#pragma unroll
            for (int nt = 0; nt < 8; ++nt) {
                float h = acc[nt][reg] + b1c[nt];
                h = h > 0.f ? h : 0.f;
                s += h * w2c[nt];
            }
            pb[reg] = s;
        }
#pragma unroll
        for (int off = 1; off < 16; off <<= 1) {
#pragma unroll
            for (int reg = 0; reg < 4; ++reg)
                pb[reg] += __shfl_xor(pb[reg], off, 64);
        }
        if (m == 0) {
#pragma unroll
            for (int reg = 0; reg < 4; ++reg) {
                int er = g * 64 + wave * 16 + q * 4 + reg;
                pred[er] = pb[reg] + bb;
            }
        }
    }
}

// ---------------------------------------------------------------------------
extern "C" void kernel_launch(void* const* d_in, const int* in_sizes, int n_in,
                              void* d_out, int out_size, void* d_ws, size_t ws_size,
                              hipStream_t stream) {
    const float* x_gene    = (const float*)d_in[0];
    const float* x_disease = (const float*)d_in[1];
    const int*   ei_g2d    = (const int*)d_in[2];
    const int*   ei_d2g    = (const int*)d_in[3];
    const int*   eli       = (const int*)d_in[6];
    const float* Wn_gene   = (const float*)d_in[7];
    const float* bn_gene   = (const float*)d_in[8];
    const float* Wn_dis    = (const float*)d_in[9];
    const float* bn_dis    = (const float*)d_in[10];
    const float* W1        = (const float*)d_in[17];
    const float* b1        = (const float*)d_in[18];
    const float* W2        = (const float*)d_in[19];
    const float* b2        = (const float*)d_in[20];

    float* out   = (float*)d_out;
    float* predp = out;                                   // [200000]
    float* zgf   = out + ELn;                             // [100000*128]
    float* zdf   = zgf + (size_t)NGn * 128;               // [100000*128]

    uint8_t* mask_d = (uint8_t*)d_ws;                     // [ND]
    uint8_t* mask_g = mask_d + NDn;                       // [NG]

    const size_t helems = (size_t)NGn * 128;              // 12.8M
    const size_t mirror_off = 200704;                     // masks, 256-aligned
    const bool   mirrorH = ws_size >= mirror_off + 2 * helems * sizeof(__bf16);
    __bf16* Hgb = mirrorH ? (__bf16*)((char*)d_ws + mirror_off) : nullptr;
    __bf16* Hdb = mirrorH ? Hgb + helems : nullptr;

    hipMemsetAsync(d_ws, 0, NGn + NDn, stream);
    scatter_mask<<<(NEn + 255) / 256, 256, 0, stream>>>(
        ei_g2d + NEn, ei_d2g + NEn, mask_d, mask_g, NEn);

    if (mirrorH) {
        // 512 blocks/side, ~3 tiles each, 2 blocks/CU co-resident
        fused_node_h<<<1024, 256, 0, stream>>>(
            x_gene, Wn_gene, bn_gene, mask_g, zgf, Hgb,
            x_disease, Wn_dis, bn_dis, mask_d, zdf, Hdb, W1);
        edge_mlp<<<2048, 256, 0, stream>>>(Hgb, Hdb, eli, b1, W2, b2, predp);
    } else {
        node_gemm<<<1024, 256, 0, stream>>>(x_gene, Wn_gene, bn_gene, mask_g, zgf, NGn);
        node_gemm<<<1024, 256, 0, stream>>>(x_disease, Wn_dis, bn_dis, mask_d, zdf, NDn);
        mlp_kernel<<<512, 256, 0, stream>>>(zgf, zdf, eli, W1, b1, W2, b2, predp);
    }
}